// Round 1
// baseline (711.771 us; speedup 1.0000x reference)
//
#include <hip/hip_runtime.h>
#include <hip/hip_bf16.h>

// Problem constants (fixed by setup_inputs / GTLModuleV1)
#define BATCH 4
#define CHAN  144
#define NPTS  16384
#define KNN   16
#define GRP   9
#define DIM   16   // CHAN / GRP

#define TILE 32

// (C, N) -> (N, C) transpose per batch slice, tiled through LDS.
__global__ __launch_bounds__(256) void transpose_kernel(
    const float* __restrict__ in, float* __restrict__ out) {
  __shared__ float tile[TILE][TILE + 1];
  const int b = blockIdx.z;
  const float* inb = in + (size_t)b * CHAN * NPTS;
  float* outb = out + (size_t)b * NPTS * CHAN;
  const int n0 = blockIdx.x * TILE;
  const int c0 = blockIdx.y * TILE;
  const int tx = threadIdx.x, ty = threadIdx.y;

  // load: rows = channels, cols = points (coalesced in n)
  #pragma unroll
  for (int i = ty; i < TILE; i += 8) {
    int c = c0 + i;
    if (c < CHAN) tile[i][tx] = inb[(size_t)c * NPTS + n0 + tx];
  }
  __syncthreads();
  // store: rows = points, cols = channels (coalesced in c)
  #pragma unroll
  for (int i = ty; i < TILE; i += 8) {
    int c = c0 + tx;
    if (c < CHAN) outb[(size_t)(n0 + i) * CHAN + c] = tile[tx][i];
  }
}

// One thread per (b, g, n). K=16 attention + softmax + weighted aggregation
// + centrality scatter, all in registers.
__global__ __launch_bounds__(256) void gtl_kernel(
    const float* __restrict__ q,    // (B, C, N) original layout
    const float* __restrict__ qT,   // (B, N, C) transposed (keys)
    const float* __restrict__ vT,   // (B, N, C) transposed (values)
    const int*   __restrict__ idx,  // (B, N, K)
    float* __restrict__ feat,       // (B, C, N)
    float* __restrict__ cent)       // (B, G, N)
{
  const int n = blockIdx.x * blockDim.x + threadIdx.x;
  const int g = blockIdx.y;
  const int b = blockIdx.z;

  // ---- self query vector: stride-1 coalesced across lanes (n fastest) ----
  const float* qb = q + ((size_t)b * CHAN + g * DIM) * NPTS + n;
  float qv[DIM];
  #pragma unroll
  for (int dd = 0; dd < DIM; ++dd) qv[dd] = qb[(size_t)dd * NPTS];

  // ---- neighbor indices: 64B contiguous per point, int4 loads ----
  int m[KNN];
  const int4* i4 = (const int4*)(idx + ((size_t)b * NPTS + n) * KNN);
  #pragma unroll
  for (int j = 0; j < 4; ++j) {
    int4 t = i4[j];
    m[4*j+0] = t.x; m[4*j+1] = t.y; m[4*j+2] = t.z; m[4*j+3] = t.w;
  }

  // ---- attention scores: gather key rows (contiguous 64B in qT) ----
  const float* qTb = qT + (size_t)b * NPTS * CHAN + g * DIM;
  float s[KNN];
  #pragma unroll
  for (int k = 0; k < KNN; ++k) {
    const float4* kr = (const float4*)(qTb + (size_t)m[k] * CHAN);
    float acc = 0.f;
    #pragma unroll
    for (int j = 0; j < 4; ++j) {
      float4 kv = kr[j];
      acc += kv.x * qv[4*j+0] + kv.y * qv[4*j+1]
           + kv.z * qv[4*j+2] + kv.w * qv[4*j+3];
    }
    s[k] = acc;
  }

  // ---- softmax over K=16 in registers ----
  float mx = s[0];
  #pragma unroll
  for (int k = 1; k < KNN; ++k) mx = fmaxf(mx, s[k]);
  float sum = 0.f;
  #pragma unroll
  for (int k = 0; k < KNN; ++k) { s[k] = __expf(s[k] - mx); sum += s[k]; }
  const float inv = 1.f / sum;

  // ---- weighted value aggregation + centrality scatter ----
  const float* vTb = vT + (size_t)b * NPTS * CHAN + g * DIM;
  float* centb = cent + ((size_t)b * GRP + g) * NPTS;
  float acc[DIM];
  #pragma unroll
  for (int dd = 0; dd < DIM; ++dd) acc[dd] = 0.f;

  #pragma unroll
  for (int k = 0; k < KNN; ++k) {
    const float w = s[k] * inv;
    const float4* vr = (const float4*)(vTb + (size_t)m[k] * CHAN);
    #pragma unroll
    for (int j = 0; j < 4; ++j) {
      float4 vv = vr[j];
      acc[4*j+0] += w * vv.x; acc[4*j+1] += w * vv.y;
      acc[4*j+2] += w * vv.z; acc[4*j+3] += w * vv.w;
    }
    atomicAdd(centb + m[k], w);
  }

  // ---- feat write: stride-1 coalesced across lanes ----
  float* fb = feat + ((size_t)b * CHAN + g * DIM) * NPTS + n;
  #pragma unroll
  for (int dd = 0; dd < DIM; ++dd) fb[(size_t)dd * NPTS] = acc[dd];
}

extern "C" void kernel_launch(void* const* d_in, const int* in_sizes, int n_in,
                              void* d_out, int out_size, void* d_ws, size_t ws_size,
                              hipStream_t stream) {
  const float* q   = (const float*)d_in[0];   // queryandkey (B,C,N)
  const float* v   = (const float*)d_in[1];   // value (B,C,N)
  const int*   idx = (const int*)d_in[2];     // idx_knn (B,N,K)

  float* feat = (float*)d_out;                              // (B,C,N)
  float* cent = feat + (size_t)BATCH * CHAN * NPTS;         // (B,G,N)

  float* qT = (float*)d_ws;                                 // (B,N,C)
  float* vT = qT + (size_t)BATCH * NPTS * CHAN;             // (B,N,C)

  // 1) transpose q, v into channel-contiguous layout for gathers
  dim3 tb(TILE, 8);
  dim3 tg(NPTS / TILE, (CHAN + TILE - 1) / TILE, BATCH);
  transpose_kernel<<<tg, tb, 0, stream>>>(q, qT);
  transpose_kernel<<<tg, tb, 0, stream>>>(v, vT);

  // 2) zero centrality output (d_out is poisoned 0xAA before each call)
  hipMemsetAsync(cent, 0, (size_t)BATCH * GRP * NPTS * sizeof(float), stream);

  // 3) main fused kernel: one thread per (b, g, n)
  dim3 gb(NPTS / 256, GRP, BATCH);
  gtl_kernel<<<gb, 256, 0, stream>>>(q, qT, vT, idx, feat, cent);
}

// Round 2
// 619.479 us; speedup vs baseline: 1.1490x; 1.1490x over previous
//
#include <hip/hip_runtime.h>

// Problem constants (fixed by setup_inputs / GTLModuleV1)
#define BATCH 4
#define CHAN  144
#define NPTS  16384
#define KNN   16
#define GRP   9
#define DIM   16   // CHAN / GRP

#define TT 32

// Fused (C,N)->(N,C) transpose for q and v, float4 on both global sides.
// grid.z in [0, 2*BATCH): z<BATCH -> q slice b=z, else v slice b=z-BATCH.
__global__ __launch_bounds__(256) void transpose2_kernel(
    const float* __restrict__ q, const float* __restrict__ v,
    float* __restrict__ qT, float* __restrict__ vT) {
  __shared__ float tile[TT][TT + 1];
  const int z = blockIdx.z;
  const int b = z & (BATCH - 1);
  const float* in = (z < BATCH ? q : v) + (size_t)b * CHAN * NPTS;
  float* out      = (z < BATCH ? qT : vT) + (size_t)b * NPTS * CHAN;
  const int n0 = blockIdx.x * TT;
  const int c0 = blockIdx.y * TT;
  const int t = threadIdx.x;

  {  // load: 32 channels x 32 points, float4 along n (coalesced)
    const int cl = t >> 3, nq = (t & 7) * 4;
    const int c = c0 + cl;
    if (c < CHAN) {
      const float4 ld = *(const float4*)&in[(size_t)c * NPTS + n0 + nq];
      tile[cl][nq + 0] = ld.x; tile[cl][nq + 1] = ld.y;
      tile[cl][nq + 2] = ld.z; tile[cl][nq + 3] = ld.w;
    }
  }
  __syncthreads();
  {  // store: 32 points x 32 channels, float4 along c (coalesced)
    const int nl = t >> 3, cq = (t & 7) * 4;
    const int c = c0 + cq;
    if (c < CHAN) {  // c multiple of 4; CHAN multiple of 4 -> full float4 ok
      float4 st;
      st.x = tile[cq + 0][nl]; st.y = tile[cq + 1][nl];
      st.z = tile[cq + 2][nl]; st.w = tile[cq + 3][nl];
      *(float4*)&out[(size_t)(n0 + nl) * CHAN + c] = st;
    }
  }
}

// Wave = 4 points x 16 dims. lane = slot*16 + d.
// Gathers: 16 contiguous lanes read one 64B-aligned row slice -> 1 line req.
__global__ __launch_bounds__(256) void gtl_kernel(
    const float* __restrict__ qT,   // (B, N, C) keys/queries
    const float* __restrict__ vT,   // (B, N, C) values
    const int*   __restrict__ idx,  // (B, N, K)
    float* __restrict__ feat,       // (B, C, N)
    float* __restrict__ cent)       // (B, G, N)
{
  const int lane = threadIdx.x & 63;
  const int wv   = threadIdx.x >> 6;        // 4 waves / block
  const int slot = lane >> 4;               // point within wave [0,4)
  const int d    = lane & 15;               // dim within group [0,16)
  const int g = blockIdx.y;
  const int b = blockIdx.z;
  const int n = blockIdx.x * 16 + wv * 4 + slot;

  // idx: lane d holds neighbor id k=d for its slot's point. Wave reads
  // 256 contiguous bytes (4 points x 16 ints) -> fully coalesced.
  const int idxv = idx[((size_t)b * NPTS + n) * KNN + d];

  // self-query element for (g*16+d) of point n: 4 x 64B segments / wave
  const float qv = qT[((size_t)b * NPTS + n) * CHAN + g * DIM + d];

  const float* qTb = qT + (size_t)b * NPTS * CHAN + g * DIM + d;
  const float* vTb = vT + (size_t)b * NPTS * CHAN + g * DIM + d;

  // ---- burst-load all 16 key rows AND 16 value rows (32 indep loads) ----
  float kd[KNN], vd[KNN];
  #pragma unroll
  for (int k = 0; k < KNN; ++k) {
    const int mk = __shfl(idxv, slot * 16 + k);
    kd[k] = qTb[(size_t)mk * CHAN];
    vd[k] = vTb[(size_t)mk * CHAN];
  }

  // ---- scores: butterfly reduce over the 16-lane dim group ----
  float s[KNN];
  #pragma unroll
  for (int k = 0; k < KNN; ++k) {
    float p = kd[k] * qv;
    p += __shfl_xor(p, 1);
    p += __shfl_xor(p, 2);
    p += __shfl_xor(p, 4);
    p += __shfl_xor(p, 8);
    s[k] = p;  // all 16 lanes of the group hold the full dot product
  }

  // ---- softmax over K=16 (redundant across lanes, registers only) ----
  float mx = s[0];
  #pragma unroll
  for (int k = 1; k < KNN; ++k) mx = fmaxf(mx, s[k]);
  float sum = 0.f;
  #pragma unroll
  for (int k = 0; k < KNN; ++k) { s[k] = __expf(s[k] - mx); sum += s[k]; }
  const float inv = 1.f / sum;

  // ---- weighted aggregation + centrality scatter ----
  float acc = 0.f;
  float* centb = cent + ((size_t)b * GRP + g) * NPTS;
  #pragma unroll
  for (int k = 0; k < KNN; ++k) {
    const float w = s[k] * inv;
    acc += w * vd[k];
    const int mk = __shfl(idxv, slot * 16 + k);  // all lanes exec the shfl
    if (d == 0) atomicAdd(centb + mk, w);        // 1 lane per point
  }

  // feat write: 16 segments of 16B per wave (d stride N, slot stride 1)
  feat[((size_t)b * CHAN + g * DIM + d) * NPTS + n] = acc;
}

extern "C" void kernel_launch(void* const* d_in, const int* in_sizes, int n_in,
                              void* d_out, int out_size, void* d_ws, size_t ws_size,
                              hipStream_t stream) {
  const float* q   = (const float*)d_in[0];   // queryandkey (B,C,N)
  const float* v   = (const float*)d_in[1];   // value (B,C,N)
  const int*   idx = (const int*)d_in[2];     // idx_knn (B,N,K)

  float* feat = (float*)d_out;                       // (B,C,N)
  float* cent = feat + (size_t)BATCH * CHAN * NPTS;  // (B,G,N)

  float* qT = (float*)d_ws;                          // (B,N,C)
  float* vT = qT + (size_t)BATCH * NPTS * CHAN;      // (B,N,C)

  // 1) fused transpose of q and v into channel-contiguous layout
  dim3 tg(NPTS / TT, (CHAN + TT - 1) / TT, BATCH * 2);
  transpose2_kernel<<<tg, 256, 0, stream>>>(q, v, qT, vT);

  // 2) zero centrality output (poisoned 0xAA before each call)
  hipMemsetAsync(cent, 0, (size_t)BATCH * GRP * NPTS * sizeof(float), stream);

  // 3) main fused kernel: wave = 4 points x 16 dims
  dim3 gb(NPTS / 16, GRP, BATCH);
  gtl_kernel<<<gb, 256, 0, stream>>>(qT, vT, idx, feat, cent);
}

// Round 3
// 444.447 us; speedup vs baseline: 1.6015x; 1.3938x over previous
//
#include <hip/hip_runtime.h>

// Problem constants (fixed by setup_inputs / GTLModuleV1)
#define BATCH 4
#define CHAN  144
#define NPTS  16384
#define KNN   16
#define GRP   9
#define DIM   16            // CHAN / GRP
#define PCHUNK 16           // partial chunks per (b,g)
#define CPTS  (NPTS / PCHUNK)  // 1024 points per block

#define TT 32

// Fused (C,N)->(N,C) transpose for q and v, float4 on both global sides.
__global__ __launch_bounds__(256) void transpose2_kernel(
    const float* __restrict__ q, const float* __restrict__ v,
    float* __restrict__ qT, float* __restrict__ vT) {
  __shared__ float tile[TT][TT + 1];
  const int z = blockIdx.z;
  const int b = z & (BATCH - 1);
  const float* in = (z < BATCH ? q : v) + (size_t)b * CHAN * NPTS;
  float* out      = (z < BATCH ? qT : vT) + (size_t)b * NPTS * CHAN;
  const int n0 = blockIdx.x * TT;
  const int c0 = blockIdx.y * TT;
  const int t = threadIdx.x;

  {  // load: 32 channels x 32 points, float4 along n (coalesced)
    const int cl = t >> 3, nq = (t & 7) * 4;
    const int c = c0 + cl;
    if (c < CHAN) {
      const float4 ld = *(const float4*)&in[(size_t)c * NPTS + n0 + nq];
      tile[cl][nq + 0] = ld.x; tile[cl][nq + 1] = ld.y;
      tile[cl][nq + 2] = ld.z; tile[cl][nq + 3] = ld.w;
    }
  }
  __syncthreads();
  {  // store: 32 points x 32 channels, float4 along c (coalesced)
    const int nl = t >> 3, cq = (t & 7) * 4;
    const int c = c0 + cq;
    if (c < CHAN) {
      float4 st;
      st.x = tile[cq + 0][nl]; st.y = tile[cq + 1][nl];
      st.z = tile[cq + 2][nl]; st.w = tile[cq + 3][nl];
      *(float4*)&out[(size_t)(n0 + nl) * CHAN + c] = st;
    }
  }
}

// Wave = 4 points x 16 dims. Block privatizes one (b,g) cent slice in LDS
// (64 KB) -> zero global atomics; flushes to per-chunk partials.
__global__ __launch_bounds__(256) void gtl_kernel(
    const float* __restrict__ qT,   // (B, N, C)
    const float* __restrict__ vT,   // (B, N, C)
    const int*   __restrict__ idx,  // (B, N, K)
    float* __restrict__ feat,       // (B, C, N)
    float* __restrict__ part)       // (B, G, PCHUNK, NPTS)
{
  __shared__ float lcent[NPTS];     // 64 KB: private cent[b,g,:] copy
  const int tid = threadIdx.x;

  // zero the LDS slice (float4, coalesced across banks)
  float4* l4 = (float4*)lcent;
  #pragma unroll
  for (int i = 0; i < NPTS / 4 / 256; ++i)
    l4[i * 256 + tid] = make_float4(0.f, 0.f, 0.f, 0.f);
  __syncthreads();

  const int lane = tid & 63;
  const int wv   = tid >> 6;        // 4 waves / block
  const int slot = lane >> 4;       // point within wave [0,4)
  const int d    = lane & 15;       // dim within group [0,16)
  const int g = blockIdx.y;
  const int b = blockIdx.z;
  const int pbase = blockIdx.x * CPTS;

  const float* qTb = qT + (size_t)b * NPTS * CHAN + g * DIM + d;
  const float* vTb = vT + (size_t)b * NPTS * CHAN + g * DIM + d;

  for (int it = 0; it < CPTS / 16; ++it) {
    const int n = pbase + it * 16 + wv * 4 + slot;

    // lane d holds neighbor id k=d of its slot's point (coalesced 256B/wave)
    const int idxv = idx[((size_t)b * NPTS + n) * KNN + d];
    const float qv = qTb[(size_t)n * CHAN];

    // burst: 16 key rows + 16 value rows; 16 contiguous lanes per 64B slice
    float kd[KNN], vd[KNN];
    #pragma unroll
    for (int k = 0; k < KNN; ++k) {
      const int mk = __shfl(idxv, slot * 16 + k);
      kd[k] = qTb[(size_t)mk * CHAN];
      vd[k] = vTb[(size_t)mk * CHAN];
    }

    // scores: butterfly reduce over the 16-lane dim group
    float s[KNN];
    #pragma unroll
    for (int k = 0; k < KNN; ++k) {
      float p = kd[k] * qv;
      p += __shfl_xor(p, 1);
      p += __shfl_xor(p, 2);
      p += __shfl_xor(p, 4);
      p += __shfl_xor(p, 8);
      s[k] = p;
    }

    // softmax over K=16 (redundant across lanes)
    float mx = s[0];
    #pragma unroll
    for (int k = 1; k < KNN; ++k) mx = fmaxf(mx, s[k]);
    float sum = 0.f;
    #pragma unroll
    for (int k = 0; k < KNN; ++k) { s[k] = __expf(s[k] - mx); sum += s[k]; }
    const float inv = 1.f / sum;

    // weighted value aggregation
    float acc = 0.f;
    #pragma unroll
    for (int k = 0; k < KNN; ++k) acc += (s[k] * inv) * vd[k];

    // centrality: each lane scatters its OWN (slot, k=d) weight -> one
    // LDS-atomic instruction per wave-iter, 64 lanes active
    float wsel = 0.f;
    #pragma unroll
    for (int k = 0; k < KNN; ++k) wsel = (d == k) ? s[k] : wsel;
    atomicAdd(&lcent[idxv], wsel * inv);

    // feat write: (B,C,N), d stride NPTS, slot stride 1
    feat[((size_t)b * CHAN + g * DIM + d) * NPTS + n] = acc;
  }

  __syncthreads();
  // flush private slice to partials (non-atomic, coalesced float4)
  float4* p4 = (float4*)(part +
      (((size_t)(b * GRP + g)) * PCHUNK + blockIdx.x) * NPTS);
  #pragma unroll
  for (int i = 0; i < NPTS / 4 / 256; ++i)
    p4[i * 256 + tid] = l4[i * 256 + tid];
}

// cent[b,g,m] = sum_p part[b,g,p,m]; thread per float4 of cent.
__global__ __launch_bounds__(256) void reduce_cent_kernel(
    const float* __restrict__ part, float* __restrict__ cent) {
  const int t = blockIdx.x * 256 + threadIdx.x;  // over 36 * 4096
  const int bg = t >> 12;
  const int m4 = (t & 4095) << 2;
  const float4* p = (const float4*)(part + ((size_t)bg * PCHUNK) * NPTS + m4);
  float4 s = make_float4(0.f, 0.f, 0.f, 0.f);
  #pragma unroll
  for (int i = 0; i < PCHUNK; ++i) {
    float4 x = p[(size_t)i * (NPTS / 4)];
    s.x += x.x; s.y += x.y; s.z += x.z; s.w += x.w;
  }
  *(float4*)(cent + (size_t)bg * NPTS + m4) = s;
}

extern "C" void kernel_launch(void* const* d_in, const int* in_sizes, int n_in,
                              void* d_out, int out_size, void* d_ws, size_t ws_size,
                              hipStream_t stream) {
  const float* q   = (const float*)d_in[0];   // queryandkey (B,C,N)
  const float* v   = (const float*)d_in[1];   // value (B,C,N)
  const int*   idx = (const int*)d_in[2];     // idx_knn (B,N,K)

  float* feat = (float*)d_out;                       // (B,C,N)
  float* cent = feat + (size_t)BATCH * CHAN * NPTS;  // (B,G,N)

  float* qT   = (float*)d_ws;                            // (B,N,C)
  float* vT   = qT + (size_t)BATCH * NPTS * CHAN;        // (B,N,C)
  float* part = vT + (size_t)BATCH * NPTS * CHAN;        // (B,G,PCHUNK,NPTS)

  // 1) fused transpose of q and v into channel-contiguous layout
  dim3 tg(NPTS / TT, (CHAN + TT - 1) / TT, BATCH * 2);
  transpose2_kernel<<<tg, 256, 0, stream>>>(q, v, qT, vT);

  // 2) main fused kernel: 576 blocks, each privatizes one cent slice in LDS
  dim3 gb(PCHUNK, GRP, BATCH);
  gtl_kernel<<<gb, 256, 0, stream>>>(qT, vT, idx, feat, part);

  // 3) reduce partials -> cent (writes every element; no memset needed)
  reduce_cent_kernel<<<(GRP * BATCH * NPTS / 4) / 256, 256, 0, stream>>>(part, cent);
}